// Round 13
// baseline (476.264 us; speedup 1.0000x reference)
//
#include <hip/hip_runtime.h>
#include <hip/hip_fp16.h>

// Problem constants (from reference)
#define Nn 50000
#define Ee 1600000
#define NRANGE 196          // ranges of 256 nodes: r = dst >> 8
#define CAP 10240           // bucket capacity (mean 8163, >20 sigma margin)
#define CHUNK 4096          // edges per partition block

typedef __attribute__((ext_vector_type(8))) short short8;
typedef __attribute__((ext_vector_type(4))) float f32x4;
typedef unsigned short ushort;
typedef unsigned int uint;

// ---------------------------------------------------------------------------
// bf16 split helpers (RNE)
// ---------------------------------------------------------------------------
__device__ __forceinline__ ushort f32_to_bf16(float f) {
    unsigned u = __builtin_bit_cast(unsigned, f);
    unsigned r = u + 0x7FFFu + ((u >> 16) & 1u);
    return (ushort)(r >> 16);
}
__device__ __forceinline__ float bf16_to_f32(ushort h) {
    unsigned u = ((unsigned)h) << 16;
    return __builtin_bit_cast(float, u);
}

// ---------------------------------------------------------------------------
// CSR build v3 (verified round 11): bucket partition -> count -> scan -> fill.
// ---------------------------------------------------------------------------

__global__ __launch_bounds__(256) void partition_kernel(const int* __restrict__ ei,
                                                        int* __restrict__ gcursor,
                                                        int2* __restrict__ buckets) {
    __shared__ int cnt[NRANGE];
    __shared__ int cur[NRANGE];
    int t = threadIdx.x;
    if (t < NRANGE) cnt[t] = 0;
    __syncthreads();
    int base = blockIdx.x * CHUNK;
    const int* __restrict__ dst = ei + Ee;
    #pragma unroll
    for (int k = 0; k < CHUNK / 256; ++k) {
        int e = base + k * 256 + t;
        if (e < Ee) atomicAdd(&cnt[dst[e] >> 8], 1);
    }
    __syncthreads();
    if (t < NRANGE) cur[t] = atomicAdd(&gcursor[t], cnt[t]);
    __syncthreads();
    #pragma unroll
    for (int k = 0; k < CHUNK / 256; ++k) {
        int e = base + k * 256 + t;
        if (e < Ee) {
            int d = dst[e];
            int r = d >> 8;
            int slot = atomicAdd(&cur[r], 1);
            if (slot < CAP) buckets[r * CAP + slot] = make_int2(ei[e], d);
        }
    }
}

__global__ __launch_bounds__(256) void count_kernel(const int2* __restrict__ buckets,
                                                    const int* __restrict__ gcursor,
                                                    int* __restrict__ counts,
                                                    float* __restrict__ dis) {
    __shared__ int cnt[256];
    int r = blockIdx.x, t = threadIdx.x;
    cnt[t] = 0;
    __syncthreads();
    int n = gcursor[r]; n = (n < CAP) ? n : CAP;
    const int2* b = buckets + (size_t)r * CAP;
    for (int i = t; i < n; i += 256) {
        int2 p = b[i];
        atomicAdd(&cnt[p.y & 255], 1);
    }
    __syncthreads();
    int node = r * 256 + t;
    if (node < Nn) {
        counts[node] = cnt[t];
        dis[node] = rsqrtf((float)(cnt[t] + 1));   // +1 self-loop
    }
}

__global__ void scan1_kernel(const int* __restrict__ counts, int* __restrict__ offsets,
                             int* __restrict__ partials) {
    __shared__ int sd[256];
    int t = threadIdx.x;
    int i = blockIdx.x * 256 + t;
    int cp = 0;
    if (i < Nn) cp = (counts[i] + 7) & ~7;   // pad run to multiple of 8
    int v = cp;
    #pragma unroll
    for (int off = 1; off < 256; off <<= 1) {
        sd[t] = v; __syncthreads();
        int add = (t >= off) ? sd[t - off] : 0;
        __syncthreads();
        v += add;
    }
    if (i < Nn) offsets[i] = v - cp;
    if (t == 255) partials[blockIdx.x] = v;
}

__global__ void scan3_kernel(int* __restrict__ offsets, const int* __restrict__ partials,
                             const int* __restrict__ counts, int* __restrict__ csr) {
    __shared__ int sd[256];
    int t = threadIdx.x;
    int s = (t < blockIdx.x) ? partials[t] : 0;   // blockIdx.x <= 195 < 256
    sd[t] = s; __syncthreads();
    #pragma unroll
    for (int off = 128; off > 0; off >>= 1) {
        if (t < off) sd[t] += sd[t + off];
        __syncthreads();
    }
    int base = sd[0];
    int i = blockIdx.x * 256 + t;
    if (i < Nn) {
        int off = offsets[i] + base;
        offsets[i] = off;
        int deg = counts[i];
        int cp  = (deg + 7) & ~7;
        for (int j = off + deg; j < off + cp; ++j) csr[j] = Nn;  // pad sentinels
        if (i == Nn - 1) offsets[Nn] = off + cp;
    }
}

__global__ __launch_bounds__(256) void fill_kernel(const int2* __restrict__ buckets,
                                                   const int* __restrict__ gcursor,
                                                   const int* __restrict__ offsets,
                                                   int* __restrict__ csr) {
    __shared__ int cur[256];
    int r = blockIdx.x, t = threadIdx.x;
    int node = r * 256 + t;
    cur[t] = (node < Nn) ? offsets[node] : 0;
    __syncthreads();
    int n = gcursor[r]; n = (n < CAP) ? n : CAP;
    const int2* b = buckets + (size_t)r * CAP;
    for (int i = t; i < n; i += 256) {
        int2 p = b[i];
        int pos = atomicAdd(&cur[p.y & 255], 1);
        csr[pos] = p.x;
    }
}

// ---------------------------------------------------------------------------
// Weight prep: split all 4 weight matrices into bf16 hi/lo planes.
// ---------------------------------------------------------------------------
__global__ void prep_w_kernel(const float* __restrict__ W1, const float* __restrict__ Wc,
                              const float* __restrict__ W2, const float* __restrict__ Wo,
                              ushort* __restrict__ base) {
    int i = blockIdx.x * 256 + threadIdx.x;  // 0..81919
    const float* src; ushort* hi; ushort* lo; int idx;
    if (i < 16384)      { src = W1; hi = base;          lo = base + 16384;  idx = i; }
    else if (i < 49152) { src = Wc; hi = base + 32768;  lo = base + 65536;  idx = i - 16384; }
    else if (i < 65536) { src = W2; hi = base + 98304;  lo = base + 114688; idx = i - 49152; }
    else                { src = Wo; hi = base + 131072; lo = base + 147456; idx = i - 65536; }
    float f = src[idx];
    ushort hb = f32_to_bf16(f);
    hi[idx] = hb;
    lo[idx] = f32_to_bf16(f - bf16_to_f32(hb));
}

// ---------------------------------------------------------------------------
// Split x into bf16 hi/lo planes (one-time, 4 el/thread, uint2 stores).
// ---------------------------------------------------------------------------
__global__ void split_x_kernel(const float* __restrict__ x, ushort* __restrict__ xhi,
                               ushort* __restrict__ xlo) {
    int i = (blockIdx.x * 256 + threadIdx.x) * 4;   // 6.4M elems, exact grid
    float4 v = *(const float4*)(x + i);
    float vv[4] = {v.x, v.y, v.z, v.w};
    ushort h[4], l[4];
    #pragma unroll
    for (int j = 0; j < 4; ++j) {
        h[j] = f32_to_bf16(vv[j]);
        l[j] = f32_to_bf16(vv[j] - bf16_to_f32(h[j]));
    }
    *(uint2*)(xhi + i) = make_uint2((uint)h[0] | ((uint)h[1] << 16),
                                    (uint)h[2] | ((uint)h[3] << 16));
    *(uint2*)(xlo + i) = make_uint2((uint)l[0] | ((uint)l[1] << 16),
                                    (uint)l[2] | ((uint)l[3] << 16));
}

// ---------------------------------------------------------------------------
// MFMA GEMM v3 (verified rounds 9-11): K=128 GEMMs (g1, g2). OUTMODE 1 = fp16.
// ---------------------------------------------------------------------------
template <int CO, int K, bool RELU, bool HASBIAS, bool SCALEDIS, int OUTMODE>
__global__ __launch_bounds__(256, 3) void mfma_gemm(
    const ushort* __restrict__ AH0, const ushort* __restrict__ AL0,
    const ushort* __restrict__ Whi, const ushort* __restrict__ Wlo,
    const float* __restrict__ bias, const float* __restrict__ dis,
    void* __restrict__ outp, ushort* __restrict__ outLo) {
    constexpr int NF = CO / 16;
    constexpr int NCH = K / 64;
    constexpr int WISS = CO / 32;

    __shared__ ushort lds[2 * 64 * 64 + 2 * CO * 64];
    ushort* ldsAh = lds;
    ushort* ldsAl = lds + 64 * 64;
    ushort* ldsWh = lds + 2 * 64 * 64;
    ushort* ldsWl = ldsWh + CO * 64;

    int tid  = threadIdx.x;
    int wave = tid >> 6;
    int lane = tid & 63;
    int c = lane & 15;
    int g = lane >> 4;
    int row0 = blockIdx.x * 64;

    f32x4 acc1[NF], acc2[NF];
    #pragma unroll
    for (int f = 0; f < NF; ++f) {
        acc1[f] = (f32x4){0.f, 0.f, 0.f, 0.f};
        acc2[f] = (f32x4){0.f, 0.f, 0.f, 0.f};
    }

    #pragma unroll
    for (int ch = 0; ch < NCH; ++ch) {
        const int k0 = ch * 64;
        #pragma unroll
        for (int i = 0; i < 2; ++i) {
            int idx = tid + i * 256;
            int row = idx >> 3, kg = idx & 7;
            int gr = row0 + row; gr = (gr < Nn) ? gr : (Nn - 1);
            int sb = (kg * 16) ^ ((row & 7) << 4);
            int ldsoff = (i * 256 + wave * 64) * 8;
            __builtin_amdgcn_global_load_lds(AH0 + (size_t)gr * 128 + k0 + (sb >> 1),
                                             &ldsAh[ldsoff], 16, 0, 0);
            __builtin_amdgcn_global_load_lds(AL0 + (size_t)gr * 128 + k0 + (sb >> 1),
                                             &ldsAl[ldsoff], 16, 0, 0);
        }
        #pragma unroll
        for (int i = 0; i < WISS; ++i) {
            int idx = tid + i * 256;
            int col = idx >> 3, kg = idx & 7;
            int sb = (kg * 16) ^ ((col & 7) << 4);
            int ldsoff = (i * 256 + wave * 64) * 8;
            __builtin_amdgcn_global_load_lds(Whi + (size_t)col * K + k0 + (sb >> 1),
                                             &ldsWh[ldsoff], 16, 0, 0);
            __builtin_amdgcn_global_load_lds(Wlo + (size_t)col * K + k0 + (sb >> 1),
                                             &ldsWl[ldsoff], 16, 0, 0);
        }
        __syncthreads();

        #pragma unroll
        for (int s = 0; s < 2; ++s) {
            int arow = wave * 16 + c;
            int ab = (s * 64 + g * 16) ^ ((arow & 7) << 4);
            short8 ahi = *(const short8*)((const char*)ldsAh + arow * 128 + ab);
            short8 alo = *(const short8*)((const char*)ldsAl + arow * 128 + ab);
            #pragma unroll
            for (int f = 0; f < NF; ++f) {
                int col = f * 16 + c;
                int wb = (s * 64 + g * 16) ^ ((col & 7) << 4);
                short8 bh = *(const short8*)((const char*)ldsWh + col * 128 + wb);
                short8 bl = *(const short8*)((const char*)ldsWl + col * 128 + wb);
                acc1[f] = __builtin_amdgcn_mfma_f32_16x16x32_bf16(ahi, bh, acc1[f], 0, 0, 0);
                acc2[f] = __builtin_amdgcn_mfma_f32_16x16x32_bf16(ahi, bl, acc2[f], 0, 0, 0);
                acc2[f] = __builtin_amdgcn_mfma_f32_16x16x32_bf16(alo, bh, acc2[f], 0, 0, 0);
            }
        }
        __syncthreads();
    }

    #pragma unroll
    for (int f = 0; f < NF; ++f) {
        int col = f * 16 + c;
        float bv = HASBIAS ? bias[col] : 0.f;
        #pragma unroll
        for (int rg = 0; rg < 4; ++rg) {
            int row = row0 + wave * 16 + g * 4 + rg;
            if (row < Nn) {
                float v = acc1[f][rg] + acc2[f][rg] + bv;
                if (RELU) v = fmaxf(v, 0.f);
                if (SCALEDIS) v *= dis[row];
                size_t idx = (size_t)row * CO + col;
                if constexpr (OUTMODE == 1) {
                    ((__half*)outp)[idx] = __float2half_rn(v);
                } else if constexpr (OUTMODE == 2) {
                    ushort hb = f32_to_bf16(v);
                    ((ushort*)outp)[idx] = hb;
                    outLo[idx] = f32_to_bf16(v - bf16_to_f32(hb));
                } else {
                    ((float*)outp)[idx] = v;
                }
            }
        }
    }
}

// ---------------------------------------------------------------------------
// FUSED propagate + concat-GEMM (K=256), 64KB-LDS version:
// Phase 1: gather the block's 64 agg rows from gbuf, dis/bias/relu, split
//          hi/lo, ds_write into persistent swizzled tile [64][128] (hi+lo =
//          32 KB). Phase 2: K-loop; ch 0-1 read the tile; ch 2-3 stage A1
//          planes into LDS that ALIASES the tile (disjoint lifetimes: tile is
//          last read in ch1; barrier precedes ch2's staging writes).
// Static LDS: 32 KB (tile/stgA union) + CO*64*2*2B W staging = 64 KB (CO=128).
// ---------------------------------------------------------------------------
template <int CO, bool RELUP, bool RELUG, int OUTMODE>
__global__ __launch_bounds__(256, 2) void fused_prop_gemm(
    const __half* __restrict__ gbuf, const int* __restrict__ offs,
    const int* __restrict__ csr, const float* __restrict__ dis,
    const float* __restrict__ biasP,
    const ushort* __restrict__ AH1, const ushort* __restrict__ AL1,
    const ushort* __restrict__ Whi, const ushort* __restrict__ Wlo,
    const float* __restrict__ biasG,
    void* __restrict__ outp, ushort* __restrict__ outLo) {
    constexpr int NF = CO / 16;
    constexpr int WISS = CO / 32;

    __shared__ ushort lds[2 * 64 * 128 + 2 * CO * 64];
    ushort* tileAh = lds;                    // [64][128] agg hi (swizzled)
    ushort* tileAl = lds + 64 * 128;         // [64][128] agg lo
    ushort* stgAh  = lds;                    // aliases tile region (ch>=2 only)
    ushort* stgAl  = lds + 64 * 64;
    ushort* stgWh  = lds + 2 * 64 * 128;     // W staging hi
    ushort* stgWl  = stgWh + CO * 64;        // W staging lo

    int tid  = threadIdx.x;
    int wave = tid >> 6;
    int lane = tid & 63;
    int c = lane & 15;
    int g = lane >> 4;
    int row0 = blockIdx.x * 64;

    // ---- phase 1: gather agg rows into persistent LDS tile ----
    for (int i = 0; i < 16; ++i) {
        int r = wave * 16 + i;
        int node = row0 + r;
        int n = (node < Nn) ? node : (Nn - 1);
        float2 sv = __half22float2(*((const __half2*)(gbuf + ((size_t)n << 7)) + lane));
        float ax = sv.x, ay = sv.y;
        int beg = offs[n], end = offs[n + 1];
        for (int e = beg; e < end; e += 8) {
            int s0 = csr[e],     s1 = csr[e + 1], s2 = csr[e + 2], s3 = csr[e + 3];
            int s4 = csr[e + 4], s5 = csr[e + 5], s6 = csr[e + 6], s7 = csr[e + 7];
            __half2 h0 = *((const __half2*)(gbuf + ((size_t)s0 << 7)) + lane);
            __half2 h1 = *((const __half2*)(gbuf + ((size_t)s1 << 7)) + lane);
            __half2 h2 = *((const __half2*)(gbuf + ((size_t)s2 << 7)) + lane);
            __half2 h3 = *((const __half2*)(gbuf + ((size_t)s3 << 7)) + lane);
            __half2 h4 = *((const __half2*)(gbuf + ((size_t)s4 << 7)) + lane);
            __half2 h5 = *((const __half2*)(gbuf + ((size_t)s5 << 7)) + lane);
            __half2 h6 = *((const __half2*)(gbuf + ((size_t)s6 << 7)) + lane);
            __half2 h7 = *((const __half2*)(gbuf + ((size_t)s7 << 7)) + lane);
            float2 v0 = __half22float2(h0), v1 = __half22float2(h1);
            float2 v2 = __half22float2(h2), v3 = __half22float2(h3);
            float2 v4 = __half22float2(h4), v5 = __half22float2(h5);
            float2 v6 = __half22float2(h6), v7 = __half22float2(h7);
            ax += ((v0.x + v1.x) + (v2.x + v3.x)) + ((v4.x + v5.x) + (v6.x + v7.x));
            ay += ((v0.y + v1.y) + (v2.y + v3.y)) + ((v4.y + v5.y) + (v6.y + v7.y));
        }
        float di = dis[n];
        ax = fmaf(di, ax, biasP[lane * 2]);
        ay = fmaf(di, ay, biasP[lane * 2 + 1]);
        if (RELUP) { ax = fmaxf(ax, 0.f); ay = fmaxf(ay, 0.f); }
        ushort hx = f32_to_bf16(ax), hy = f32_to_bf16(ay);
        ushort lx = f32_to_bf16(ax - bf16_to_f32(hx));
        ushort ly = f32_to_bf16(ay - bf16_to_f32(hy));
        int sb = (4 * lane) ^ ((r & 7) << 4);     // same involution the K-loop reads
        *(uint*)((char*)tileAh + r * 256 + sb) = (uint)hx | ((uint)hy << 16);
        *(uint*)((char*)tileAl + r * 256 + sb) = (uint)lx | ((uint)ly << 16);
    }
    __syncthreads();

    // ---- phase 2: K-loop (K=256) ----
    f32x4 acc1[NF], acc2[NF];
    #pragma unroll
    for (int f = 0; f < NF; ++f) {
        acc1[f] = (f32x4){0.f, 0.f, 0.f, 0.f};
        acc2[f] = (f32x4){0.f, 0.f, 0.f, 0.f};
    }

    #pragma unroll
    for (int ch = 0; ch < 4; ++ch) {
        const int k0 = ch * 64;
        if (ch >= 2) {
            // tile region is dead now (last read in ch1, barrier passed) ->
            // stage A1 into the aliased stgA buffers.
            const int kb = k0 - 128;
            #pragma unroll
            for (int i = 0; i < 2; ++i) {
                int idx = tid + i * 256;
                int row = idx >> 3, kg = idx & 7;
                int gr = row0 + row; gr = (gr < Nn) ? gr : (Nn - 1);
                int sb = (kg * 16) ^ ((row & 7) << 4);
                int ldsoff = (i * 256 + wave * 64) * 8;
                __builtin_amdgcn_global_load_lds(AH1 + (size_t)gr * 128 + kb + (sb >> 1),
                                                 &stgAh[ldsoff], 16, 0, 0);
                __builtin_amdgcn_global_load_lds(AL1 + (size_t)gr * 128 + kb + (sb >> 1),
                                                 &stgAl[ldsoff], 16, 0, 0);
            }
        }
        #pragma unroll
        for (int i = 0; i < WISS; ++i) {
            int idx = tid + i * 256;
            int col = idx >> 3, kg = idx & 7;
            int sb = (kg * 16) ^ ((col & 7) << 4);
            int ldsoff = (i * 256 + wave * 64) * 8;
            __builtin_amdgcn_global_load_lds(Whi + (size_t)col * 256 + k0 + (sb >> 1),
                                             &stgWh[ldsoff], 16, 0, 0);
            __builtin_amdgcn_global_load_lds(Wlo + (size_t)col * 256 + k0 + (sb >> 1),
                                             &stgWl[ldsoff], 16, 0, 0);
        }
        __syncthreads();

        #pragma unroll
        for (int s = 0; s < 2; ++s) {
            int arow = wave * 16 + c;
            short8 ahi, alo;
            if (ch < 2) {
                int ab = (ch * 128 + s * 64 + g * 16) ^ ((arow & 7) << 4);
                ahi = *(const short8*)((const char*)tileAh + arow * 256 + ab);
                alo = *(const short8*)((const char*)tileAl + arow * 256 + ab);
            } else {
                int ab = (s * 64 + g * 16) ^ ((arow & 7) << 4);
                ahi = *(const short8*)((const char*)stgAh + arow * 128 + ab);
                alo = *(const short8*)((const char*)stgAl + arow * 128 + ab);
            }
            #pragma unroll
            for (int f = 0; f < NF; ++f) {
                int col = f * 16 + c;
                int wb = (s * 64 + g * 16) ^ ((col & 7) << 4);
                short8 bh = *(const short8*)((const char*)stgWh + col * 128 + wb);
                short8 bl = *(const short8*)((const char*)stgWl + col * 128 + wb);
                acc1[f] = __builtin_amdgcn_mfma_f32_16x16x32_bf16(ahi, bh, acc1[f], 0, 0, 0);
                acc2[f] = __builtin_amdgcn_mfma_f32_16x16x32_bf16(ahi, bl, acc2[f], 0, 0, 0);
                acc2[f] = __builtin_amdgcn_mfma_f32_16x16x32_bf16(alo, bh, acc2[f], 0, 0, 0);
            }
        }
        __syncthreads();
    }

    #pragma unroll
    for (int f = 0; f < NF; ++f) {
        int col = f * 16 + c;
        float bv = biasG[col];
        #pragma unroll
        for (int rg = 0; rg < 4; ++rg) {
            int row = row0 + wave * 16 + g * 4 + rg;
            if (row < Nn) {
                float v = acc1[f][rg] + acc2[f][rg] + bv;
                if (RELUG) v = fmaxf(v, 0.f);
                size_t idx = (size_t)row * CO + col;
                if constexpr (OUTMODE == 2) {
                    ushort hb = f32_to_bf16(v);
                    ((ushort*)outp)[idx] = hb;
                    outLo[idx] = f32_to_bf16(v - bf16_to_f32(hb));
                } else {
                    ((float*)outp)[idx] = v;
                }
            }
        }
    }
}

// ---------------------------------------------------------------------------

extern "C" void kernel_launch(void* const* d_in, const int* in_sizes, int n_in,
                              void* d_out, int out_size, void* d_ws, size_t ws_size,
                              hipStream_t stream) {
    const float* x  = (const float*)d_in[0];
    const int*   ei = (const int*)d_in[1];   // [2][E]: src then dst
    const float* W1 = (const float*)d_in[2];
    const float* b1 = (const float*)d_in[3];
    const float* Wc = (const float*)d_in[4];
    const float* bc = (const float*)d_in[5];
    const float* W2 = (const float*)d_in[6];
    const float* b2 = (const float*)d_in[7];
    const float* Wo = (const float*)d_in[8];
    const float* bo = (const float*)d_in[9];
    float* out = (float*)d_out;

    // workspace carve-up (256B aligned)
    char* base = (char*)d_ws;
    auto carve = [&](size_t bytes) {
        void* p = (void*)base;
        base += (bytes + 255) & ~(size_t)255;
        return p;
    };
    char*  tmp      = (char*)carve(512 * 1024);
    int*   gcursor  = (int*)tmp;                        // 784 B
    int*   counts   = (int*)(tmp + 1024);               // 200 KB
    ushort* wplanes = (ushort*)tmp;                     // 320 KB, after fill
    int*   offsets  = (int*)carve((Nn + 1) * sizeof(int));
    int*   partials = (int*)carve(256 * sizeof(int));
    float* dis      = (float*)carve(Nn * sizeof(float));
    int2*  buckets  = (int2*)carve((size_t)NRANGE * CAP * sizeof(int2));  // 16 MB
    int*   csr      = (int*)carve(((size_t)Ee + 8 * Nn) * sizeof(int));   // padded
    __half* gbuf    = (__half*)carve((size_t)(Nn + 2) * 128 * sizeof(__half));
    ushort* xhi     = (ushort*)carve((size_t)Nn * 128 * sizeof(ushort));
    ushort* xlo     = (ushort*)carve((size_t)Nn * 128 * sizeof(ushort));
    ushort* combHi  = (ushort*)carve((size_t)Nn * 128 * sizeof(ushort));
    ushort* combLo  = (ushort*)carve((size_t)Nn * 128 * sizeof(ushort));

    const ushort* w1hi = wplanes;
    const ushort* w1lo = wplanes + 16384;
    const ushort* wchi = wplanes + 32768;
    const ushort* wclo = wplanes + 65536;
    const ushort* w2hi = wplanes + 98304;
    const ushort* w2lo = wplanes + 114688;
    const ushort* wohi = wplanes + 131072;
    const ushort* wolo = wplanes + 147456;

    const int SCAN_BLOCKS = (Nn + 255) / 256;       // 196
    const int PBLOCKS = (Ee + CHUNK - 1) / CHUNK;   // 391

    // --- CSR build v3 (bucket partition, LDS-atomic ranks) ---
    hipMemsetAsync(gcursor, 0, NRANGE * sizeof(int), stream);
    hipMemsetAsync(gbuf + (size_t)Nn * 128, 0, 256, stream);  // zero sentinel row
    partition_kernel<<<PBLOCKS, 256, 0, stream>>>(ei, gcursor, buckets);
    count_kernel<<<NRANGE, 256, 0, stream>>>(buckets, gcursor, counts, dis);
    scan1_kernel<<<SCAN_BLOCKS, 256, 0, stream>>>(counts, offsets, partials);
    scan3_kernel<<<SCAN_BLOCKS, 256, 0, stream>>>(offsets, partials, counts, csr);
    fill_kernel<<<NRANGE, 256, 0, stream>>>(buckets, gcursor, offsets, csr);

    // --- weight prep (aliases dead gcursor/counts space) + x split ---
    prep_w_kernel<<<320, 256, 0, stream>>>(W1, Wc, W2, Wo, (ushort*)wplanes);
    split_x_kernel<<<6250, 256, 0, stream>>>(x, xhi, xlo);

    const int GB = (Nn + 63) / 64;   // 782

    // g1 = fp16( dis * (x @ W1^T) )                          -> gbuf
    mfma_gemm<128, 128, false, false, true, 1><<<GB, 256, 0, stream>>>(
        xhi, xlo, w1hi, w1lo, nullptr, dis, gbuf, nullptr);
    // x_comb = relu([relu(prop(g1)+b1), x] @ Wc^T + bc)      -> comb planes (fused)
    fused_prop_gemm<128, true, true, 2><<<GB, 256, 0, stream>>>(
        gbuf, offsets, csr, dis, b1, xhi, xlo, wchi, wclo, bc, combHi, combLo);
    // g2 = fp16( dis * (x_comb @ W2^T) )                     -> gbuf
    mfma_gemm<128, 128, false, false, true, 1><<<GB, 256, 0, stream>>>(
        combHi, combLo, w2hi, w2lo, nullptr, dis, gbuf, nullptr);
    // out = [prop(g2)+b2, x_comb] @ Wo^T + bo                -> d_out (fused)
    fused_prop_gemm<64, false, false, 0><<<GB, 256, 0, stream>>>(
        gbuf, offsets, csr, dis, b2, combHi, combLo, wohi, wolo, bo, out, nullptr);
}

// Round 14
// 331.153 us; speedup vs baseline: 1.4382x; 1.4382x over previous
//
#include <hip/hip_runtime.h>
#include <hip/hip_fp16.h>

// Problem constants (from reference)
#define Nn 50000
#define Ee 1600000
#define NRANGE 196          // ranges of 256 nodes: r = dst >> 8
#define CAP 10240           // bucket capacity (mean 8163, >20 sigma margin)
#define CHUNK 4096          // edges per partition block

typedef __attribute__((ext_vector_type(8))) short short8;
typedef __attribute__((ext_vector_type(4))) float f32x4;
typedef unsigned short ushort;
typedef unsigned int uint;

// ---------------------------------------------------------------------------
// bf16 split helpers (RNE)
// ---------------------------------------------------------------------------
__device__ __forceinline__ ushort f32_to_bf16(float f) {
    unsigned u = __builtin_bit_cast(unsigned, f);
    unsigned r = u + 0x7FFFu + ((u >> 16) & 1u);
    return (ushort)(r >> 16);
}
__device__ __forceinline__ float bf16_to_f32(ushort h) {
    unsigned u = ((unsigned)h) << 16;
    return __builtin_bit_cast(float, u);
}

// ---------------------------------------------------------------------------
// CSR build v3b: bucket partition with PACKED 4B entries ((src<<8)|dst&255;
// src < 50000 < 2^16 so 24 bits suffice) -> count -> scan -> LDS-cursor fill.
// ---------------------------------------------------------------------------

__global__ __launch_bounds__(256) void partition_kernel(const int* __restrict__ ei,
                                                        int* __restrict__ gcursor,
                                                        uint* __restrict__ buckets) {
    __shared__ int cnt[NRANGE];
    __shared__ int cur[NRANGE];
    int t = threadIdx.x;
    if (t < NRANGE) cnt[t] = 0;
    __syncthreads();
    int base = blockIdx.x * CHUNK;
    const int* __restrict__ dst = ei + Ee;
    #pragma unroll
    for (int k = 0; k < CHUNK / 256; ++k) {
        int e = base + k * 256 + t;
        if (e < Ee) atomicAdd(&cnt[dst[e] >> 8], 1);
    }
    __syncthreads();
    if (t < NRANGE) cur[t] = atomicAdd(&gcursor[t], cnt[t]);
    __syncthreads();
    #pragma unroll
    for (int k = 0; k < CHUNK / 256; ++k) {
        int e = base + k * 256 + t;
        if (e < Ee) {
            int d = dst[e];
            int r = d >> 8;
            int slot = atomicAdd(&cur[r], 1);
            if (slot < CAP) buckets[r * CAP + slot] = ((uint)ei[e] << 8) | (uint)(d & 255);
        }
    }
}

__global__ __launch_bounds__(256) void count_kernel(const uint* __restrict__ buckets,
                                                    const int* __restrict__ gcursor,
                                                    int* __restrict__ counts,
                                                    float* __restrict__ dis) {
    __shared__ int cnt[256];
    int r = blockIdx.x, t = threadIdx.x;
    cnt[t] = 0;
    __syncthreads();
    int n = gcursor[r]; n = (n < CAP) ? n : CAP;
    const uint* b = buckets + (size_t)r * CAP;
    for (int i = t; i < n; i += 256) {
        atomicAdd(&cnt[b[i] & 255u], 1);
    }
    __syncthreads();
    int node = r * 256 + t;
    if (node < Nn) {
        counts[node] = cnt[t];
        dis[node] = rsqrtf((float)(cnt[t] + 1));   // +1 self-loop
    }
}

__global__ void scan1_kernel(const int* __restrict__ counts, int* __restrict__ offsets,
                             int* __restrict__ partials) {
    __shared__ int sd[256];
    int t = threadIdx.x;
    int i = blockIdx.x * 256 + t;
    int cp = 0;
    if (i < Nn) cp = (counts[i] + 7) & ~7;   // pad run to multiple of 8
    int v = cp;
    #pragma unroll
    for (int off = 1; off < 256; off <<= 1) {
        sd[t] = v; __syncthreads();
        int add = (t >= off) ? sd[t - off] : 0;
        __syncthreads();
        v += add;
    }
    if (i < Nn) offsets[i] = v - cp;
    if (t == 255) partials[blockIdx.x] = v;
}

__global__ void scan3_kernel(int* __restrict__ offsets, const int* __restrict__ partials,
                             const int* __restrict__ counts, int* __restrict__ csr) {
    __shared__ int sd[256];
    int t = threadIdx.x;
    int s = (t < blockIdx.x) ? partials[t] : 0;   // blockIdx.x <= 195 < 256
    sd[t] = s; __syncthreads();
    #pragma unroll
    for (int off = 128; off > 0; off >>= 1) {
        if (t < off) sd[t] += sd[t + off];
        __syncthreads();
    }
    int base = sd[0];
    int i = blockIdx.x * 256 + t;
    if (i < Nn) {
        int off = offsets[i] + base;
        offsets[i] = off;
        int deg = counts[i];
        int cp  = (deg + 7) & ~7;
        for (int j = off + deg; j < off + cp; ++j) csr[j] = Nn;  // pad sentinels
        if (i == Nn - 1) offsets[Nn] = off + cp;
    }
}

__global__ __launch_bounds__(256) void fill_kernel(const uint* __restrict__ buckets,
                                                   const int* __restrict__ gcursor,
                                                   const int* __restrict__ offsets,
                                                   int* __restrict__ csr) {
    __shared__ int cur[256];
    int r = blockIdx.x, t = threadIdx.x;
    int node = r * 256 + t;
    cur[t] = (node < Nn) ? offsets[node] : 0;
    __syncthreads();
    int n = gcursor[r]; n = (n < CAP) ? n : CAP;
    const uint* b = buckets + (size_t)r * CAP;
    for (int i = t; i < n; i += 256) {
        uint p = b[i];
        int pos = atomicAdd(&cur[p & 255u], 1);
        csr[pos] = (int)(p >> 8);
    }
}

// ---------------------------------------------------------------------------
// Merged prep: blocks [0,6250) split x into bf16 hi/lo planes; blocks
// [6250,6570) split the 4 weight matrices.
// ---------------------------------------------------------------------------
__global__ void prep_split_kernel(const float* __restrict__ x, ushort* __restrict__ xhi,
                                  ushort* __restrict__ xlo,
                                  const float* __restrict__ W1, const float* __restrict__ Wc,
                                  const float* __restrict__ W2, const float* __restrict__ Wo,
                                  ushort* __restrict__ wbase) {
    if (blockIdx.x < 6250) {
        int i = (blockIdx.x * 256 + threadIdx.x) * 4;   // 6.4M elems, exact
        float4 v = *(const float4*)(x + i);
        float vv[4] = {v.x, v.y, v.z, v.w};
        ushort h[4], l[4];
        #pragma unroll
        for (int j = 0; j < 4; ++j) {
            h[j] = f32_to_bf16(vv[j]);
            l[j] = f32_to_bf16(vv[j] - bf16_to_f32(h[j]));
        }
        *(uint2*)(xhi + i) = make_uint2((uint)h[0] | ((uint)h[1] << 16),
                                        (uint)h[2] | ((uint)h[3] << 16));
        *(uint2*)(xlo + i) = make_uint2((uint)l[0] | ((uint)l[1] << 16),
                                        (uint)l[2] | ((uint)l[3] << 16));
    } else {
        int i = (blockIdx.x - 6250) * 256 + threadIdx.x;  // 0..81919
        const float* src; ushort* hi; ushort* lo; int idx;
        if (i < 16384)      { src = W1; hi = wbase;          lo = wbase + 16384;  idx = i; }
        else if (i < 49152) { src = Wc; hi = wbase + 32768;  lo = wbase + 65536;  idx = i - 16384; }
        else if (i < 65536) { src = W2; hi = wbase + 98304;  lo = wbase + 114688; idx = i - 49152; }
        else                { src = Wo; hi = wbase + 131072; lo = wbase + 147456; idx = i - 65536; }
        float f = src[idx];
        ushort hb = f32_to_bf16(f);
        hi[idx] = hb;
        lo[idx] = f32_to_bf16(f - bf16_to_f32(hb));
    }
}

// ---------------------------------------------------------------------------
// MFMA GEMM v3 (verified rounds 9-11): LDS-staged, swizzled, BK=64.
// OUTMODE: 0=f32, 1=fp16 (gather buf), 2=bf16 hi/lo planes.
// ---------------------------------------------------------------------------
template <int CO, int K, bool RELU, bool HASBIAS, bool SCALEDIS, int OUTMODE>
__global__ __launch_bounds__(256, 3) void mfma_gemm(
    const ushort* __restrict__ AH0, const ushort* __restrict__ AL0,
    const ushort* __restrict__ AH1, const ushort* __restrict__ AL1,
    const ushort* __restrict__ Whi, const ushort* __restrict__ Wlo,
    const float* __restrict__ bias, const float* __restrict__ dis,
    void* __restrict__ outp, ushort* __restrict__ outLo) {
    constexpr int NF = CO / 16;
    constexpr int NCH = K / 64;
    constexpr int WISS = CO / 32;

    __shared__ ushort lds[2 * 64 * 64 + 2 * CO * 64];
    ushort* ldsAh = lds;
    ushort* ldsAl = lds + 64 * 64;
    ushort* ldsWh = lds + 2 * 64 * 64;
    ushort* ldsWl = ldsWh + CO * 64;

    int tid  = threadIdx.x;
    int wave = tid >> 6;
    int lane = tid & 63;
    int c = lane & 15;
    int g = lane >> 4;
    int row0 = blockIdx.x * 64;

    f32x4 acc1[NF], acc2[NF];
    #pragma unroll
    for (int f = 0; f < NF; ++f) {
        acc1[f] = (f32x4){0.f, 0.f, 0.f, 0.f};
        acc2[f] = (f32x4){0.f, 0.f, 0.f, 0.f};
    }

    #pragma unroll
    for (int ch = 0; ch < NCH; ++ch) {
        const int k0 = ch * 64;
        const ushort* Ah = (K == 256 && k0 >= 128) ? AH1 : AH0;
        const ushort* Al = (K == 256 && k0 >= 128) ? AL1 : AL0;
        const int kb = (K == 256 && k0 >= 128) ? (k0 - 128) : k0;

        #pragma unroll
        for (int i = 0; i < 2; ++i) {
            int idx = tid + i * 256;
            int row = idx >> 3, kg = idx & 7;
            int gr = row0 + row; gr = (gr < Nn) ? gr : (Nn - 1);
            int sb = (kg * 16) ^ ((row & 7) << 4);
            int ldsoff = (i * 256 + wave * 64) * 8;
            __builtin_amdgcn_global_load_lds(Ah + (size_t)gr * 128 + kb + (sb >> 1),
                                             &ldsAh[ldsoff], 16, 0, 0);
            __builtin_amdgcn_global_load_lds(Al + (size_t)gr * 128 + kb + (sb >> 1),
                                             &ldsAl[ldsoff], 16, 0, 0);
        }
        #pragma unroll
        for (int i = 0; i < WISS; ++i) {
            int idx = tid + i * 256;
            int col = idx >> 3, kg = idx & 7;
            int sb = (kg * 16) ^ ((col & 7) << 4);
            int ldsoff = (i * 256 + wave * 64) * 8;
            __builtin_amdgcn_global_load_lds(Whi + (size_t)col * K + k0 + (sb >> 1),
                                             &ldsWh[ldsoff], 16, 0, 0);
            __builtin_amdgcn_global_load_lds(Wlo + (size_t)col * K + k0 + (sb >> 1),
                                             &ldsWl[ldsoff], 16, 0, 0);
        }
        __syncthreads();

        #pragma unroll
        for (int s = 0; s < 2; ++s) {
            int arow = wave * 16 + c;
            int ab = (s * 64 + g * 16) ^ ((arow & 7) << 4);
            short8 ahi = *(const short8*)((const char*)ldsAh + arow * 128 + ab);
            short8 alo = *(const short8*)((const char*)ldsAl + arow * 128 + ab);
            #pragma unroll
            for (int f = 0; f < NF; ++f) {
                int col = f * 16 + c;
                int wb = (s * 64 + g * 16) ^ ((col & 7) << 4);
                short8 bh = *(const short8*)((const char*)ldsWh + col * 128 + wb);
                short8 bl = *(const short8*)((const char*)ldsWl + col * 128 + wb);
                acc1[f] = __builtin_amdgcn_mfma_f32_16x16x32_bf16(ahi, bh, acc1[f], 0, 0, 0);
                acc2[f] = __builtin_amdgcn_mfma_f32_16x16x32_bf16(ahi, bl, acc2[f], 0, 0, 0);
                acc2[f] = __builtin_amdgcn_mfma_f32_16x16x32_bf16(alo, bh, acc2[f], 0, 0, 0);
            }
        }
        __syncthreads();
    }

    #pragma unroll
    for (int f = 0; f < NF; ++f) {
        int col = f * 16 + c;
        float bv = HASBIAS ? bias[col] : 0.f;
        #pragma unroll
        for (int rg = 0; rg < 4; ++rg) {
            int row = row0 + wave * 16 + g * 4 + rg;
            if (row < Nn) {
                float v = acc1[f][rg] + acc2[f][rg] + bv;
                if (RELU) v = fmaxf(v, 0.f);
                if (SCALEDIS) v *= dis[row];
                size_t idx = (size_t)row * CO + col;
                if constexpr (OUTMODE == 1) {
                    ((__half*)outp)[idx] = __float2half_rn(v);
                } else if constexpr (OUTMODE == 2) {
                    ushort hb = f32_to_bf16(v);
                    ((ushort*)outp)[idx] = hb;
                    outLo[idx] = f32_to_bf16(v - bf16_to_f32(hb));
                } else {
                    ((float*)outp)[idx] = v;
                }
            }
        }
    }
}

// ---------------------------------------------------------------------------
// Propagation in g-form, fp16 gather rows (256B/row), x8-padded runs.
// VALU-reduced body: tree-reduce each 8-edge group in fp16 (__hadd2 x7),
// one cvt + 2 f32 adds per group (vs 16 cvt + 16 add before). Group error
// ~3 fp16 roundings; f32 across groups -> adds <~1e-3 worst-case at output.
// ---------------------------------------------------------------------------
template <bool RELU>
__global__ __launch_bounds__(256) void propagate_kernel(
    const __half* __restrict__ gbuf, const int* __restrict__ offs,
    const int* __restrict__ csr, const float* __restrict__ dis,
    const float* __restrict__ bias, ushort* __restrict__ outHi,
    ushort* __restrict__ outLo) {
    int node = blockIdx.x * 4 + (threadIdx.x >> 6);
    if (node >= Nn) return;
    int lane = threadIdx.x & 63;
    float2 sv = __half22float2(*((const __half2*)(gbuf + ((size_t)node << 7)) + lane));
    float ax = sv.x, ay = sv.y;
    int beg = offs[node], end = offs[node + 1];
    for (int e = beg; e < end; e += 8) {
        int s0 = csr[e],     s1 = csr[e + 1], s2 = csr[e + 2], s3 = csr[e + 3];
        int s4 = csr[e + 4], s5 = csr[e + 5], s6 = csr[e + 6], s7 = csr[e + 7];
        __half2 h0 = *((const __half2*)(gbuf + ((size_t)s0 << 7)) + lane);
        __half2 h1 = *((const __half2*)(gbuf + ((size_t)s1 << 7)) + lane);
        __half2 h2 = *((const __half2*)(gbuf + ((size_t)s2 << 7)) + lane);
        __half2 h3 = *((const __half2*)(gbuf + ((size_t)s3 << 7)) + lane);
        __half2 h4 = *((const __half2*)(gbuf + ((size_t)s4 << 7)) + lane);
        __half2 h5 = *((const __half2*)(gbuf + ((size_t)s5 << 7)) + lane);
        __half2 h6 = *((const __half2*)(gbuf + ((size_t)s6 << 7)) + lane);
        __half2 h7 = *((const __half2*)(gbuf + ((size_t)s7 << 7)) + lane);
        __half2 t0 = __hadd2(h0, h1), t1 = __hadd2(h2, h3);
        __half2 t2 = __hadd2(h4, h5), t3 = __hadd2(h6, h7);
        t0 = __hadd2(t0, t1);
        t2 = __hadd2(t2, t3);
        t0 = __hadd2(t0, t2);
        float2 v = __half22float2(t0);
        ax += v.x;
        ay += v.y;
    }
    float di = dis[node];
    ax = fmaf(di, ax, bias[lane * 2]);
    ay = fmaf(di, ay, bias[lane * 2 + 1]);
    if (RELU) { ax = fmaxf(ax, 0.f); ay = fmaxf(ay, 0.f); }
    ushort hx = f32_to_bf16(ax), hy = f32_to_bf16(ay);
    ushort lx = f32_to_bf16(ax - bf16_to_f32(hx));
    ushort ly = f32_to_bf16(ay - bf16_to_f32(hy));
    ((uint*)(outHi + ((size_t)node << 7)))[lane] = (uint)hx | ((uint)hy << 16);
    ((uint*)(outLo + ((size_t)node << 7)))[lane] = (uint)lx | ((uint)ly << 16);
}

// ---------------------------------------------------------------------------

extern "C" void kernel_launch(void* const* d_in, const int* in_sizes, int n_in,
                              void* d_out, int out_size, void* d_ws, size_t ws_size,
                              hipStream_t stream) {
    const float* x  = (const float*)d_in[0];
    const int*   ei = (const int*)d_in[1];   // [2][E]: src then dst
    const float* W1 = (const float*)d_in[2];
    const float* b1 = (const float*)d_in[3];
    const float* Wc = (const float*)d_in[4];
    const float* bc = (const float*)d_in[5];
    const float* W2 = (const float*)d_in[6];
    const float* b2 = (const float*)d_in[7];
    const float* Wo = (const float*)d_in[8];
    const float* bo = (const float*)d_in[9];
    float* out = (float*)d_out;

    // workspace carve-up (256B aligned)
    char* base = (char*)d_ws;
    auto carve = [&](size_t bytes) {
        void* p = (void*)base;
        base += (bytes + 255) & ~(size_t)255;
        return p;
    };
    char*  tmp      = (char*)carve(512 * 1024);
    int*   gcursor  = (int*)tmp;                        // 784 B
    int*   counts   = (int*)(tmp + 1024);               // 200 KB
    ushort* wplanes = (ushort*)tmp;                     // 320 KB, after fill
    int*   offsets  = (int*)carve((Nn + 1) * sizeof(int));
    int*   partials = (int*)carve(256 * sizeof(int));
    float* dis      = (float*)carve(Nn * sizeof(float));
    uint*  buckets  = (uint*)carve((size_t)NRANGE * CAP * sizeof(uint));  // 8 MB
    int*   csr      = (int*)carve(((size_t)Ee + 8 * Nn) * sizeof(int));   // padded
    __half* gbuf    = (__half*)carve((size_t)(Nn + 2) * 128 * sizeof(__half));
    ushort* xhi     = (ushort*)carve((size_t)Nn * 128 * sizeof(ushort));
    ushort* xlo     = (ushort*)carve((size_t)Nn * 128 * sizeof(ushort));
    ushort* aggHi   = (ushort*)carve((size_t)Nn * 128 * sizeof(ushort));  // also agg2
    ushort* aggLo   = (ushort*)carve((size_t)Nn * 128 * sizeof(ushort));
    ushort* combHi  = (ushort*)carve((size_t)Nn * 128 * sizeof(ushort));
    ushort* combLo  = (ushort*)carve((size_t)Nn * 128 * sizeof(ushort));

    const ushort* w1hi = wplanes;
    const ushort* w1lo = wplanes + 16384;
    const ushort* wchi = wplanes + 32768;
    const ushort* wclo = wplanes + 65536;
    const ushort* w2hi = wplanes + 98304;
    const ushort* w2lo = wplanes + 114688;
    const ushort* wohi = wplanes + 131072;
    const ushort* wolo = wplanes + 147456;

    const int SCAN_BLOCKS = (Nn + 255) / 256;       // 196
    const int PBLOCKS = (Ee + CHUNK - 1) / CHUNK;   // 391

    // --- CSR build v3b (packed buckets, LDS-atomic ranks) ---
    hipMemsetAsync(gcursor, 0, NRANGE * sizeof(int), stream);
    hipMemsetAsync(gbuf + (size_t)Nn * 128, 0, 256, stream);  // zero sentinel row
    partition_kernel<<<PBLOCKS, 256, 0, stream>>>(ei, gcursor, buckets);
    count_kernel<<<NRANGE, 256, 0, stream>>>(buckets, gcursor, counts, dis);
    scan1_kernel<<<SCAN_BLOCKS, 256, 0, stream>>>(counts, offsets, partials);
    scan3_kernel<<<SCAN_BLOCKS, 256, 0, stream>>>(offsets, partials, counts, csr);
    fill_kernel<<<NRANGE, 256, 0, stream>>>(buckets, gcursor, offsets, csr);

    // --- merged x-split + weight prep (aliases dead gcursor/counts space) ---
    prep_split_kernel<<<6570, 256, 0, stream>>>(x, xhi, xlo, W1, Wc, W2, Wo,
                                                (ushort*)wplanes);

    const int GB = (Nn + 63) / 64;   // 782
    const int PB = (Nn + 3) / 4;     // 12500

    // g1 = fp16( dis * (x @ W1^T) )                  -> gbuf
    mfma_gemm<128, 128, false, false, true, 1><<<GB, 256, 0, stream>>>(
        xhi, xlo, nullptr, nullptr, w1hi, w1lo, nullptr, dis, gbuf, nullptr);
    // x_agg = relu(dis*(sum g1) + b1)                -> agg hi/lo planes
    propagate_kernel<true><<<PB, 256, 0, stream>>>(gbuf, offsets, csr, dis, b1, aggHi, aggLo);
    // x_comb = relu([x_agg, x] @ Wc^T + bc)          -> comb hi/lo planes
    mfma_gemm<128, 256, true, true, false, 2><<<GB, 256, 0, stream>>>(
        aggHi, aggLo, xhi, xlo, wchi, wclo, bc, nullptr, combHi, combLo);
    // g2 = fp16( dis * (x_comb @ W2^T) )             -> gbuf
    mfma_gemm<128, 128, false, false, true, 1><<<GB, 256, 0, stream>>>(
        combHi, combLo, nullptr, nullptr, w2hi, w2lo, nullptr, dis, gbuf, nullptr);
    // agg2 = dis*(sum g2) + b2                       -> agg planes (reuse)
    propagate_kernel<false><<<PB, 256, 0, stream>>>(gbuf, offsets, csr, dis, b2, aggHi, aggLo);
    // out = [agg2, x_comb] @ Wo^T + bo               -> d_out (f32)
    mfma_gemm<64, 256, false, true, false, 0><<<GB, 256, 0, stream>>>(
        aggHi, aggLo, combHi, combLo, wohi, wolo, bo, nullptr, out, nullptr);
}